// Round 9
// baseline (285.338 us; speedup 1.0000x reference)
//
#include <hip/hip_runtime.h>
#include <math.h>

#define BB 16
#define H 1024
#define W 1024
#define HW (H*W)
#define NTOT (BB*HW)
#define CAP 262144u

typedef unsigned long long u64;

// float32 of np.exp(-0.5*(n/1)^2), n=-2..2 (correctly-rounded decimal literals)
__device__ __constant__ float GW[5] = {
    0.13533528323661270f, 0.60653065971263342f, 1.0f,
    0.60653065971263342f, 0.13533528323661270f};

// NMS neighbor offsets per direction bucket
// 0:E 1:SE 2:S 3:SW 4:W 5:NW 6:N 7:NE
__device__ __constant__ int NBDY[8] = {0, 1, 1, 1, 0, -1, -1, -1};
__device__ __constant__ int NBDX[8] = {1, 1, 0, -1, -1, -1, 0, 1};

#define CSCALE ((float)(180.0 / 3.1415926))

// =====================================================================
// K1: fully fused gaussian(h)+gaussian(v)+sobel+mag+bucket+NMS.
// Tile 64x16 output px. LDS 15360 B. r6-measured-best layout (sA stride
// 80; the stride-84 "conflict fix" was refuted in r8: conflicts 20.6M ->
// 20.8M, dur 114 -> 122, so reverted).
// __launch_bounds__(256) with NO min-waves: measured VGPR use is 40,
// so the allocator needs no cap; at <=64 regs + 15.4KB LDS the HW can
// run 8 blocks/CU (32 waves) vs 6 under (256,6). ((256,8) is avoided:
// r1 showed it makes the compiler spill catastrophically.)
// Layout (all overlays barrier-separated):
//   sA[24*80]  : img rows y0-4..y0+19, cols x0-8..x0+71 (col c <-> x0-8+c)
//                -> overlay sm rows y0-2..y0+17 (col s <-> x0-6+s)
//                -> tail: sBk (18*18 ushort @ float 1600), redS @ 1800
//                  (rows 20-23 of sA are dead after stage B)
//   sB[24*76]  : gh rows 24, col s <-> x0-6+s
//                -> overlay mag rows y0-1..y0+16 (col cm <-> x0-4+cm)
// NMS division-free; uncertain tie band excluded + fixup list (k_post).
// =====================================================================
__global__ __launch_bounds__(256) void k_smooth_sobel_nms(
    const float* __restrict__ img, float* __restrict__ thin,
    float* __restrict__ partialA, float* __restrict__ partialB,
    unsigned int* __restrict__ cnt, uint4* __restrict__ list) {
#pragma clang fp contract(off)
    __shared__ float sA[24 * 80];
    __shared__ float sB[24 * 76];
    unsigned short* sBk = (unsigned short*)&sA[1600];  // 18*18 ushort = 648 B
    float* redS = &sA[1800];                           // 8 floats scratch

    const int tid = threadIdx.x;
    const int x0 = blockIdx.x * 64;
    const int y0 = blockIdx.y * 16;
    const int b = blockIdx.z;
    const size_t base = (size_t)b * HW;

    // ---- stage A: img tile + halo: 24 rows x 20 quads (cols x0-8..x0+71) ----
    for (int idx = tid; idx < 24 * 20; idx += 256) {
        int r = idx / 20, v = idx - r * 20;
        int gy = y0 - 4 + r;
        int gxv = x0 - 8 + v * 4;
        float4 val = make_float4(0.f, 0.f, 0.f, 0.f);
        if (gy >= 0 && gy < H && gxv >= 0 && gxv <= W - 4)
            val = *(const float4*)&img[base + (size_t)gy * W + gxv];
        *(float4*)&sA[r * 80 + v * 4] = val;
    }
    __syncthreads();

    // ---- stage B: horizontal gaussian, 24 rows x 19 quads (cols x0-6..x0+69) ----
    for (int idx = tid; idx < 24 * 19; idx += 256) {
        int r = idx / 19, g = idx - r * 19;
        const float* p = &sA[r * 80 + g * 4];
        float4 A0 = *(const float4*)p;
        float4 A1 = *(const float4*)(p + 4);
        float a_[8] = {A0.x, A0.y, A0.z, A0.w, A1.x, A1.y, A1.z, A1.w};
        float o[4];
#pragma unroll
        for (int j = 0; j < 4; ++j) {
            float s = 0.0f;
#pragma unroll
            for (int k = 0; k < 5; ++k) s = s + GW[k] * a_[j + k];
            o[j] = s;
        }
        *(float4*)&sB[r * 76 + g * 4] = make_float4(o[0], o[1], o[2], o[3]);
    }
    __syncthreads();

    // ---- stage C: vertical gaussian -> sm (overlays sA), ZERO at image OOB ----
    for (int idx = tid; idx < 20 * 19; idx += 256) {
        int rr = idx / 19, g = idx - rr * 19;
        float bb[20];
#pragma unroll
        for (int k = 0; k < 5; ++k) {
            float4 t = *(const float4*)&sB[(rr + k) * 76 + g * 4];
            bb[k * 4 + 0] = t.x; bb[k * 4 + 1] = t.y;
            bb[k * 4 + 2] = t.z; bb[k * 4 + 3] = t.w;
        }
        int gy = y0 - 2 + rr;
        bool rowok = (gy >= 0 && gy < H);
        float o[4];
#pragma unroll
        for (int j = 0; j < 4; ++j) {
            float s = 0.0f;
#pragma unroll
            for (int k = 0; k < 5; ++k) s = s + GW[k] * bb[k * 4 + j];
            int gx = x0 - 6 + g * 4 + j;
            o[j] = (rowok && gx >= 0 && gx < W) ? s : 0.0f;
        }
        *(float4*)&sA[rr * 80 + g * 4] = make_float4(o[0], o[1], o[2], o[3]);
    }
    __syncthreads();

    // ---- stage D: sobel + mag + bucket over mag tile (18 rows x 72 cols) ----
    for (int idx = tid; idx < 18 * 18; idx += 256) {
        int m = idx / 18, gq = idx - m * 18;
        const float* P0 = &sA[m * 80 + gq * 4];   // sm rows m..m+2
        const float* P1 = P0 + 80;
        const float* P2 = P1 + 80;
        float4 q0 = *(const float4*)P0; float4 e0 = *(const float4*)(P0 + 4);
        float4 q1 = *(const float4*)P1; float4 e1 = *(const float4*)(P1 + 4);
        float4 q2 = *(const float4*)P2; float4 e2 = *(const float4*)(P2 + 4);
        float r0[8] = {q0.x, q0.y, q0.z, q0.w, e0.x, e0.y, e0.z, e0.w};
        float r1[8] = {q1.x, q1.y, q1.z, q1.w, e1.x, e1.y, e1.z, e1.w};
        float r2[8] = {q2.x, q2.y, q2.z, q2.w, e2.x, e2.y, e2.z, e2.w};
        int gy = y0 - 1 + m;
        unsigned int bk = 0;
        float mg[4];
#pragma unroll
        for (int j = 0; j < 4; ++j) {
            float a00 = r0[j + 1], a01 = r0[j + 2], a02 = r0[j + 3];
            float a10 = r1[j + 1],                  a12 = r1[j + 3];
            float a20 = r2[j + 1], a21 = r2[j + 2], a22 = r2[j + 3];

            float Ix = a00;
            Ix = Ix - a02;
            Ix = Ix + 2.0f * a10;
            Ix = Ix - 2.0f * a12;
            Ix = Ix + a20;
            Ix = Ix - a22;

            float Iy = a00;
            Iy = Iy + 2.0f * a01;
            Iy = Iy + a02;
            Iy = Iy - a20;
            Iy = Iy - 2.0f * a21;
            Iy = Iy - a22;

            float t1 = Ix * Ix;
            float t2 = Iy * Iy;
            float m2 = sqrtf(t1 + t2);
            int gx = x0 - 4 + gq * 4 + j;
            if (gy < 0 || gy >= H || gx < 0 || gx >= W) m2 = 0.0f;  // zero-pad like ref
            mg[j] = m2;

            // octant by comparisons; conservative band -> exact double fallback
            float ax = fabsf(Ix), ay = fabsf(Iy);
            float mn = fminf(ax, ay), mx = fmaxf(ax, ay);
            float cr = mn * 0.92387953f - mx * 0.38268343f;
            int bidx;
            if (fabsf(cr) < mx * 3e-5f) {
                float fa2 = (float)atan2((double)Iy, (double)Ix);
                float d2 = fa2 * CSCALE;
                d2 = d2 + 180.0f;
                float t2d = d2 / 45.0f;
                float rr2 = rintf(t2d);
                bidx = ((int)rr2) & 7;
            } else if (ay <= ax * 0.41421356f) {
                bidx = signbit(Ix) ? 0 : 4;
            } else if (ay >= ax * 2.41421356f) {
                bidx = (Iy >= 0.0f) ? 6 : 2;
            } else {
                bidx = (Iy >= 0.0f) ? ((Ix >= 0.0f) ? 5 : 7)
                                    : ((Ix >= 0.0f) ? 3 : 1);
            }
            bk |= ((unsigned int)bidx) << (4 * j);
        }
        *(float4*)&sB[m * 76 + gq * 4] = make_float4(mg[0], mg[1], mg[2], mg[3]);
        sBk[m * 18 + gq] = (unsigned short)bk;
    }
    __syncthreads();

    // ---- stage E: NMS (division-free) + thin write + block maxima ----
    const int r = tid >> 4;            // 0..15
    const int cg = (tid & 15) * 4;     // 0..60
    const int y = y0 + r;
    const int m = r + 1;
    float tmax = 0.0f, amax = 0.0f;
    {
        unsigned int bk4 = sBk[m * 18 + (cg >> 2) + 1];
        float4 a4 = *(const float4*)&sB[m * 76 + cg + 4];
        float av[4] = {a4.x, a4.y, a4.z, a4.w};
        float o[4];
#pragma unroll
        for (int j = 0; j < 4; ++j) {
            int bkt = (bk4 >> (4 * j)) & 7;
            int dy = NBDY[bkt], dx = NBDX[bkt];
            int cm = cg + 4 + j;
            float a = av[j];
            float bp = sB[(m + dy) * 76 + cm + dx];
            float bn = sB[(m - dy) * 76 + cm - dx];
            bool g1 = a > bp, g2 = a > bn;
            bool im = g1 && g2;
            if (im) {
                bool f1 = a >= bp * 1.0000005f;
                bool f2 = a >= bn * 1.0000005f;
                if (!(f1 && f2)) {
                    // uncertain tie band: conservatively exclude, log for fixup
                    im = false;
                    unsigned int id = atomicAdd(cnt, 1u);
                    if (id < CAP) {
                        uint4 e;
                        e.x = (unsigned int)(base + (size_t)y * W + x0 + cg + j);
                        e.y = __float_as_uint(a);
                        e.z = __float_as_uint(bp);
                        e.w = __float_as_uint(bn);
                        list[id] = e;
                    }
                }
            }
            tmax = fmaxf(tmax, a);          // raw magmax over ALL interior px
            if (im) amax = fmaxf(amax, a);  // thin max over confirmed px
            o[j] = im ? a : 0.0f;
        }
        *(float4*)&thin[base + (size_t)y * W + x0 + cg] =
            make_float4(o[0], o[1], o[2], o[3]);
    }
#pragma unroll
    for (int off = 32; off > 0; off >>= 1) {
        tmax = fmaxf(tmax, __shfl_down(tmax, off));
        amax = fmaxf(amax, __shfl_down(amax, off));
    }
    if ((tid & 63) == 0) { redS[tid >> 6] = tmax; redS[4 + (tid >> 6)] = amax; }
    __syncthreads();
    if (tid == 0) {
        float tA = fmaxf(fmaxf(redS[0], redS[1]), fmaxf(redS[2], redS[3]));
        float tB = fmaxf(fmaxf(redS[4], redS[5]), fmaxf(redS[6], redS[7]));
        int pb = (b * 64 + blockIdx.y) * 16 + blockIdx.x;  // 1024 per image
        partialA[pb] = tA;
        partialB[pb] = tB;
    }
}

// =====================================================================
// k_post (single block, 1024 thr): per-image magmax M -> fixup the
// uncertain-tie list (exact division path, adds-only) -> per-image thin
// max (partials + fixup adds) -> global thin max + threshold bisection.
// =====================================================================
__global__ __launch_bounds__(1024) void k_post(const float* __restrict__ partialA,
                                               const float* __restrict__ partialB,
                                               const unsigned int* __restrict__ cnt,
                                               const uint4* __restrict__ list,
                                               float* __restrict__ thin,
                                               float* __restrict__ hdr,
                                               float* __restrict__ thr) {
#pragma clang fp contract(off)
    __shared__ float sM[16];
    __shared__ int sAmaxI[16];   // float-as-int (>=0) thin-max additions
    __shared__ float sTm[16];
    __shared__ float sTmAll;
    const int tid = threadIdx.x;
    const int iw = tid >> 6, lane = tid & 63;   // wave iw owns image iw

    // phase A: per-image magmax
    {
        const float* p = partialA + iw * 1024;
        float m = 0.0f;
        for (int k = lane; k < 1024; k += 64) m = fmaxf(m, p[k]);
        for (int off = 32; off > 0; off >>= 1) m = fmaxf(m, __shfl_down(m, off));
        if (lane == 0) { sM[iw] = m; sAmaxI[iw] = 0; hdr[iw] = m; }
    }
    __syncthreads();

    // phase B: fixup uncertain NMS ties (only ADDS pixels)
    {
        unsigned int n = *cnt;
        if (n > CAP) n = CAP;
        for (unsigned int i = tid; i < n; i += 1024) {
            uint4 e = list[i];
            float a = __uint_as_float(e.y);
            float bp = __uint_as_float(e.z);
            float bn = __uint_as_float(e.w);
            int b = (int)(e.x >> 20);
            float M = sM[b];
            // appended only when g1&&g2 held; resolve strict > after /M exactly
            bool f1 = a >= bp * 1.0000005f;
            bool f2 = a >= bn * 1.0000005f;
            float qa = a / M;
            bool r1 = f1 ? true : (qa > (bp / M));
            bool r2 = f2 ? true : (qa > (bn / M));
            if (r1 && r2) {
                thin[e.x] = a;
                atomicMax(&sAmaxI[b], __float_as_int(a));
            }
        }
    }
    __syncthreads();

    // phase C: per-image thin max -> normalized (RN monotone => exact)
    {
        const float* p = partialB + iw * 1024;
        float m = 0.0f;
        for (int k = lane; k < 1024; k += 64) m = fmaxf(m, p[k]);
        for (int off = 32; off > 0; off >>= 1) m = fmaxf(m, __shfl_down(m, off));
        if (lane == 0) {
            m = fmaxf(m, __int_as_float(sAmaxI[iw]));
            sTm[iw] = m / sM[iw];
        }
    }
    __syncthreads();
    if (tid == 0) {
        float tm = 0.0f;
        for (int i = 0; i < 16; ++i) tm = fmaxf(tm, sTm[i]);
        hdr[16] = tm;
        sTmAll = tm;
    }
    __syncthreads();
    // threshold bisection: smallest float x with x/M >= T
    if (tid < 32) {
        float tm = sTmAll;
        int t = tid;
        float M = sM[t >> 1];
        float T = (t & 1) ? (tm * 0.15f) : 0.00392f;
        if (0.0f / M >= T) { thr[t] = 0.0f; return; }
        unsigned int lo = 0u, hi = 0x7f800000u;
        while (hi - lo > 1u) {
            unsigned int mid = lo + ((hi - lo) >> 1);
            if (__uint_as_float(mid) / M >= T) hi = mid; else lo = mid;
        }
        thr[t] = __uint_as_float(hi);
    }
}

// ---------------- threshold: thin -> Sb/Wb (no division, no Mb) ----------------
__global__ __launch_bounds__(256, 8) void k_thresh_b(const float* __restrict__ thin,
                                                     const float* __restrict__ hdr,
                                                     const float* __restrict__ thr,
                                                     u64* __restrict__ Sb,
                                                     u64* __restrict__ Wb) {
    __shared__ unsigned int nibS[256], nibW[256];
    const int tid = threadIdx.x;
    const int x0 = blockIdx.x * 128;
    const int y0 = blockIdx.y * 32;
    const int b = blockIdx.z;
    const size_t base = (size_t)b * HW;
    const float Alo = thr[b * 2], Ahi = thr[b * 2 + 1];
    const bool snm = (hdr[16] * 0.15f <= 0.0f);
    const int r = tid >> 5;
    const int cg = (tid & 31) * 4;

    for (int k4 = 0; k4 < 4; ++k4) {
        const int rr = k4 * 8 + r;
        const int y = y0 + rr;
        float4 a4 = *(const float4*)&thin[base + (size_t)y * W + x0 + cg];
        float av[4] = {a4.x, a4.y, a4.z, a4.w};
        unsigned int ns = 0, nw = 0;
#pragma unroll
        for (int j = 0; j < 4; ++j) {
            bool strong = snm || (av[j] >= Ahi);
            bool weak = (!strong) && (av[j] >= Alo);
            ns |= (strong ? 1u : 0u) << j;
            nw |= (weak ? 1u : 0u) << j;
        }
        nibS[tid] = ns;
        nibW[tid] = nw;
        __syncthreads();
        if (tid < 32) {
            bool isW = (tid >= 16);
            int t = tid & 15;
            int rw = t >> 1, h = t & 1;
            const unsigned int* nb = isW ? nibW : nibS;
            u64 w = 0;
#pragma unroll
            for (int j = 0; j < 16; ++j)
                w |= (u64)nb[rw * 32 + h * 16 + j] << (4 * j);
            int yy = y0 + k4 * 8 + rw;
            int widx2 = ((b << 8) | ((yy >> 6) << 4) | ((x0 >> 6) + h)) * 64 + (yy & 63);
            if (isW) Wb[widx2] = w; else Sb[widx2] = w;
        }
        __syncthreads();
    }
}

// ---------------- hysteresis: bit-parallel 64x64 tile per wave ----------------
// r8 post-mortem: LOW_T=0.00392 => Wk is DENSE (almost every px weak), so
// components span whole tiles. Plain dilation: ~160 iters/pass. H-KS alone:
// rows fill instantly but vertical still 1 row/iter => ~64 iters at 2.5x
// cost = measured wash. Fix: V-Kogge-Stone (segmented vertical flood through
// weak columns, shfl-doubling with prefix-AND masks). One iteration now =
// full H flood + diagonal step + full V flood => ~3-6 iters for dense masks.
// HIP __shfl_up/down clamp to own value at the edges, so edge terms
// degenerate to y |= y & P (no-ops) -- no explicit masking needed.
// Monotone operator, iterated to in-tile convergence => same per-pass
// fixpoint as the verified r6/r8 kernels => bit-identical output.
template <bool LAST>
__global__ __launch_bounds__(256) void k_hyster_bits(const u64* __restrict__ Wb,
                                                     u64* __restrict__ Sb,
                                                     float* __restrict__ out) {
    const int lane = threadIdx.x & 63;
    const int t = blockIdx.x * 4 + (threadIdx.x >> 6);  // tile id = b*256+ty*16+tx
    const int ty = (t >> 4) & 15;
    const int tx = t & 15;
    const int idx = t * 64 + lane;

    u64 S = Sb[idx];
    const u64 Wk = Wb[idx];

    u64 hstat = 0;
    if (tx > 0)  hstat |= (Sb[(t - 1) * 64 + lane] >> 63) & 1ull;
    if (tx < 15) hstat |= (Sb[(t + 1) * 64 + lane] & 1ull) << 63;

    u64 halo = 0;
    if (lane == 0 && ty > 0) {
        const int ta = t - 16;
        u64 tc = Sb[ta * 64 + 63];
        u64 hh = (tc << 1) | tc | (tc >> 1);
        if (tx > 0)  hh |= (Sb[(ta - 1) * 64 + 63] >> 63) & 1ull;
        if (tx < 15) hh |= (Sb[(ta + 1) * 64 + 63] & 1ull) << 63;
        halo = hh;
    }
    if (lane == 63 && ty < 15) {
        const int tb = t + 16;
        u64 tc = Sb[tb * 64 + 0];
        u64 hh = (tc << 1) | tc | (tc >> 1);
        if (tx > 0)  hh |= (Sb[(tb - 1) * 64 + 0] >> 63) & 1ull;
        if (tx < 15) hh |= (Sb[(tb + 1) * 64 + 0] & 1ull) << 63;
        halo = hh;
    }

    // one-time injection of constant external sources (hstat own/up/dn + halo)
    {
        u64 eu = __shfl_up(hstat, 1, 64);
        u64 ed = __shfl_down(hstat, 1, 64);
        if (lane == 0)  eu = halo;
        if (lane == 63) ed = halo;
        S |= Wk & (hstat | eu | ed);
    }

    for (int it = 0; it < 160; ++it) {
        // ---- horizontal flood of S through weak runs (Kogge-Stone) ----
        u64 x = S;
        x |= (x << 1) & Wk;
        x |= (x >> 1) & Wk;
        u64 pL = Wk & (Wk << 1);
        u64 pR = Wk & (Wk >> 1);
        x |= (x << 2) & pL;   x |= (x >> 2) & pR;
        pL &= pL << 2;        pR &= pR >> 2;
        x |= (x << 4) & pL;   x |= (x >> 4) & pR;
        pL &= pL << 4;        pR &= pR >> 4;
        x |= (x << 8) & pL;   x |= (x >> 8) & pR;
        pL &= pL << 8;        pR &= pR >> 8;
        x |= (x << 16) & pL;  x |= (x >> 16) & pR;
        pL &= pL << 16;       pR &= pR >> 16;
        x |= (x << 32) & pL;  x |= (x >> 32) & pR;
        // ---- vertical single step with diagonal spill (8-connectivity) ----
        u64 hh = x | (x << 1) | (x >> 1);
        u64 up = __shfl_up(hh, 1, 64);
        if (lane == 0) up = 0;
        u64 dn = __shfl_down(hh, 1, 64);
        if (lane == 63) dn = 0;
        u64 y = x | (Wk & (up | dn));
        // ---- V-KS: same-column flood through weak runs, downward ----
        {
            u64 P = Wk;
            y |= __shfl_up(y, 1, 64) & P;
            u64 P2 = P & __shfl_up(P, 1, 64);
            y |= __shfl_up(y, 2, 64) & P2;
            u64 P4 = P2 & __shfl_up(P2, 2, 64);
            y |= __shfl_up(y, 4, 64) & P4;
            u64 P8 = P4 & __shfl_up(P4, 4, 64);
            y |= __shfl_up(y, 8, 64) & P8;
            u64 P16 = P8 & __shfl_up(P8, 8, 64);
            y |= __shfl_up(y, 16, 64) & P16;
            u64 P32 = P16 & __shfl_up(P16, 16, 64);
            y |= __shfl_up(y, 32, 64) & P32;
        }
        // ---- V-KS upward ----
        {
            u64 P = Wk;
            y |= __shfl_down(y, 1, 64) & P;
            u64 P2 = P & __shfl_down(P, 1, 64);
            y |= __shfl_down(y, 2, 64) & P2;
            u64 P4 = P2 & __shfl_down(P2, 2, 64);
            y |= __shfl_down(y, 4, 64) & P4;
            u64 P8 = P4 & __shfl_down(P4, 4, 64);
            y |= __shfl_down(y, 8, 64) & P8;
            u64 P16 = P8 & __shfl_down(P8, 8, 64);
            y |= __shfl_down(y, 16, 64) & P16;
            u64 P32 = P16 & __shfl_down(P16, 16, 64);
            y |= __shfl_down(y, 32, 64) & P32;
        }
        bool ch = (y != S);
        S = y;
        if (!__any(ch)) break;
    }

    if (!LAST) {
        Sb[idx] = S;
    } else {
        const int bimg = t >> 8;
        float* op = out + (size_t)bimg * HW + (size_t)(ty * 64) * W + tx * 64 + lane;
#pragma unroll 4
        for (int rr = 0; rr < 64; ++rr) {
            u64 wrow = __shfl(S, rr, 64);
            op[(size_t)rr * W] = ((wrow >> lane) & 1ull) ? 255.0f : 0.0f;
        }
    }
}

extern "C" void kernel_launch(void* const* d_in, const int* in_sizes, int n_in,
                              void* d_out, int out_size, void* d_ws, size_t ws_size,
                              hipStream_t stream) {
    (void)in_sizes; (void)n_in; (void)out_size; (void)ws_size;
    const float* img = (const float*)d_in[0];
    float* out = (float*)d_out;

    // workspace layout
    float* hdr = (float*)d_ws;                       // [0..15]=magmax, [16]=thinmax
    float* thr = hdr + 64;                           // 32 floats: per-image Alo/Ahi
    unsigned int* cnt = (unsigned int*)(hdr + 96);   // fixup-list counter
    float* partialA = hdr + 128;                     // 16384 floats (K1 raw magmax)
    float* partialB = partialA + 16384;              // 16384 floats (K1 raw thinmax)
    uint4* list = (uint4*)(partialB + 16384);        // CAP entries * 16 B = 4 MB
    float* thin = (float*)((char*)list + (size_t)CAP * 16);  // 64 MB
    u64* Sb = (u64*)(thin + (size_t)NTOT);           // strong bits, 2 MB
    u64* Wb = Sb + NTOT / 64;                        // weak bits, 2 MB

    hipMemsetAsync(cnt, 0, sizeof(unsigned int), stream);

    dim3 blk(256);
    k_smooth_sobel_nms<<<dim3(16, 64, BB), blk, 0, stream>>>(img, thin, partialA,
                                                             partialB, cnt, list);
    k_post<<<dim3(1), dim3(1024), 0, stream>>>(partialA, partialB, cnt, list,
                                               thin, hdr, thr);
    k_thresh_b<<<dim3(8, 32, BB), blk, 0, stream>>>(thin, hdr, thr, Sb, Wb);
    for (int p = 0; p < 5; ++p)
        k_hyster_bits<false><<<dim3(NTOT / (64 * 64) / 4), blk, 0, stream>>>(Wb, Sb, out);
    k_hyster_bits<true><<<dim3(NTOT / (64 * 64) / 4), blk, 0, stream>>>(Wb, Sb, out);
}

// Round 10
// 247.166 us; speedup vs baseline: 1.1544x; 1.1544x over previous
//
#include <hip/hip_runtime.h>
#include <math.h>

#define BB 16
#define H 1024
#define W 1024
#define HW (H*W)
#define NTOT (BB*HW)

typedef unsigned long long u64;

// float32 of np.exp(-0.5*(n/1)^2), n=-2..2 (correctly-rounded decimal literals)
__device__ __constant__ float GW[5] = {
    0.13533528323661270f, 0.60653065971263342f, 1.0f,
    0.60653065971263342f, 0.13533528323661270f};

// NMS neighbor offsets per direction bucket
// 0:E 1:SE 2:S 3:SW 4:W 5:NW 6:N 7:NE
__device__ __constant__ int NBDY[8] = {0, 1, 1, 1, 0, -1, -1, -1};
__device__ __constant__ int NBDX[8] = {1, 1, 0, -1, -1, -1, 0, 1};

#define CSCALE ((float)(180.0 / 3.1415926))

// =====================================================================
// K1: fused gaussian(h)+gaussian(v)+sobel+mag+bucket + per-block magmax
// Tile 128x8. LDS ~16.2 KB -> 8 blocks/CU (wave cap). Bucket by pure
// comparisons (exact outside a conservative boundary band; band falls
// back to the proven exact double-atan2 chain).
// [r0-r9 evidence: this un-fused split (64 us K1) beats every fused
//  K1+NMS variant (114-143 us) -- the pipeline is VALU-bound, so
//  recomputing sobel over halo + scattered NMS reads costs more than
//  the 96 MB of HBM traffic fusion saves at 26% HBM utilization.]
// =====================================================================
#define TW 128
#define TH 8
// sA: img rows y0-3..y0+10 (14), cols x0-4..x0+131 (136 w), stride 136 (+slack)
// sB: gh  rows 14, stride 132 (cols 130/131 garbage-fed but never consumed)
// sm overlays sA: rows 10 <-> y0-1..y0+8, col c <-> x0-1+c (zeroed if OOB)
__global__ __launch_bounds__(256, 8) void k_smooth_sobel(const float* __restrict__ img,
                                                         float* __restrict__ mag,
                                                         unsigned char* __restrict__ bucket,
                                                         float* __restrict__ partial) {
#pragma clang fp contract(off)
    __shared__ float sA[14 * 136 + 16];
    __shared__ float sB[14 * 132];
    __shared__ float red[256];

    const int tid = threadIdx.x;
    const int x0 = blockIdx.x * TW;
    const int y0 = blockIdx.y * TH;
    const int b = blockIdx.z;
    const size_t base = (size_t)b * HW;

    // ---- stage A: load img tile + halo (float4, all-or-nothing per vec) ----
    for (int idx = tid; idx < 14 * 34; idx += 256) {
        int r = idx / 34, v = idx - r * 34;
        int gy = y0 - 3 + r;
        int gxv = x0 - 4 + v * 4;
        float4 val = make_float4(0.f, 0.f, 0.f, 0.f);
        if (gy >= 0 && gy < H && gxv >= 0 && gxv <= W - 4)
            val = *(const float4*)&img[base + (size_t)gy * W + gxv];
        *(float4*)&sA[r * 136 + v * 4] = val;
    }
    __syncthreads();

    // ---- stage B: horizontal gaussian, 4 cols/iter ----
    for (int idx = tid; idx < 14 * 33; idx += 256) {
        int r = idx / 33, g = idx - r * 33;
        const float* p = &sA[r * 136 + g * 4];
        float4 A0 = *(const float4*)p;
        float4 A1 = *(const float4*)(p + 4);
        float4 A2 = *(const float4*)(p + 8);
        float a_[12] = {A0.x, A0.y, A0.z, A0.w, A1.x, A1.y, A1.z, A1.w,
                        A2.x, A2.y, A2.z, A2.w};
        float o[4];
#pragma unroll
        for (int j = 0; j < 4; ++j) {
            float s = 0.0f;
#pragma unroll
            for (int k = 0; k < 5; ++k) s = s + GW[k] * a_[j + 1 + k];
            o[j] = s;
        }
        *(float4*)&sB[r * 132 + g * 4] = make_float4(o[0], o[1], o[2], o[3]);
    }
    __syncthreads();

    // ---- stage C: vertical gaussian -> sm (overlays sA), ZERO at image OOB ----
    for (int idx = tid; idx < 10 * 33; idx += 256) {
        int rr = idx / 33, g = idx - rr * 33;
        float bb[20];
#pragma unroll
        for (int k = 0; k < 5; ++k) {
            float4 t = *(const float4*)&sB[(rr + k) * 132 + g * 4];
            bb[k * 4 + 0] = t.x; bb[k * 4 + 1] = t.y;
            bb[k * 4 + 2] = t.z; bb[k * 4 + 3] = t.w;
        }
        int gy = y0 - 1 + rr;
        bool rowok = (gy >= 0 && gy < H);
        float o[4];
#pragma unroll
        for (int j = 0; j < 4; ++j) {
            float s = 0.0f;
#pragma unroll
            for (int k = 0; k < 5; ++k) s = s + GW[k] * bb[k * 4 + j];
            int gx = x0 - 1 + g * 4 + j;
            o[j] = (rowok && gx >= 0 && gx < W) ? s : 0.0f;
        }
        *(float4*)&sA[rr * 136 + g * 4] = make_float4(o[0], o[1], o[2], o[3]);
    }
    __syncthreads();

    // ---- stage D: sobel + mag + bucket (comparisons), 4 px/thread ----
    const int r = tid >> 5;            // 0..7
    const int cg = (tid & 31) * 4;     // 0..124
    const int y = y0 + r;
    const float* P0 = &sA[r * 136 + cg];
    const float* P1 = P0 + 136;
    const float* P2 = P1 + 136;
    float4 q0 = *(const float4*)P0; float2 e0 = *(const float2*)(P0 + 4);
    float4 q1 = *(const float4*)P1; float2 e1 = *(const float2*)(P1 + 4);
    float4 q2 = *(const float4*)P2; float2 e2 = *(const float2*)(P2 + 4);
    float r0[6] = {q0.x, q0.y, q0.z, q0.w, e0.x, e0.y};
    float r1[6] = {q1.x, q1.y, q1.z, q1.w, e1.x, e1.y};
    float r2[6] = {q2.x, q2.y, q2.z, q2.w, e2.x, e2.y};

    float tmax = 0.0f;
    float mg[4];
    unsigned int bk = 0;
#pragma unroll
    for (int j = 0; j < 4; ++j) {
        float a00 = r0[j], a01 = r0[j + 1], a02 = r0[j + 2];
        float a10 = r1[j],                  a12 = r1[j + 2];
        float a20 = r2[j], a21 = r2[j + 1], a22 = r2[j + 2];

        float Ix = a00;
        Ix = Ix - a02;
        Ix = Ix + 2.0f * a10;
        Ix = Ix - 2.0f * a12;
        Ix = Ix + a20;
        Ix = Ix - a22;

        float Iy = a00;
        Iy = Iy + 2.0f * a01;
        Iy = Iy + a02;
        Iy = Iy - a20;
        Iy = Iy - 2.0f * a21;
        Iy = Iy - a22;

        float t1 = Ix * Ix;
        float t2 = Iy * Iy;
        float m = sqrtf(t1 + t2);
        mg[j] = m;
        tmax = fmaxf(tmax, m);

        // octant by comparisons; conservative band -> exact double fallback
        float ax = fabsf(Ix), ay = fabsf(Iy);
        float mn = fminf(ax, ay), mx = fmaxf(ax, ay);
        float cr = mn * 0.92387953f - mx * 0.38268343f;  // r*sin(alpha-22.5deg)
        int bidx;
        if (fabsf(cr) < mx * 3e-5f) {
            float fa2 = (float)atan2((double)Iy, (double)Ix);
            float d2 = fa2 * CSCALE;
            d2 = d2 + 180.0f;
            float t2d = d2 / 45.0f;
            float rr2 = rintf(t2d);
            bidx = ((int)rr2) & 7;
        } else if (ay <= ax * 0.41421356f) {          // near-horizontal
            bidx = signbit(Ix) ? 0 : 4;
        } else if (ay >= ax * 2.41421356f) {          // near-vertical
            bidx = (Iy >= 0.0f) ? 6 : 2;
        } else {                                      // diagonal
            bidx = (Iy >= 0.0f) ? ((Ix >= 0.0f) ? 5 : 7)
                                : ((Ix >= 0.0f) ? 3 : 1);
        }
        bk |= ((unsigned int)bidx) << (8 * j);
    }
    *(float4*)&mag[base + (size_t)y * W + x0 + cg] = make_float4(mg[0], mg[1], mg[2], mg[3]);
    *(unsigned int*)&bucket[base + (size_t)y * W + x0 + cg] = bk;

    red[tid] = tmax;
    __syncthreads();
    for (int s = 128; s > 0; s >>= 1) {
        if (tid < s) red[tid] = fmaxf(red[tid], red[tid + s]);
        __syncthreads();
    }
    if (tid == 0) {
        int pb = (blockIdx.z * 128 + blockIdx.y) * 8 + blockIdx.x;  // 1024 per image
        partial[pb] = red[0];
    }
}

// ---------------- per-image max over 1024 block partials ----------------
__global__ __launch_bounds__(256) void k_redmax_img(const float* __restrict__ partial,
                                                    float* __restrict__ magmax) {
    __shared__ float red[256];
    const float* p = partial + blockIdx.x * 1024;
    float m = 0.0f;
    for (int k = threadIdx.x; k < 1024; k += 256) m = fmaxf(m, p[k]);
    red[threadIdx.x] = m;
    __syncthreads();
    for (int s = 128; s > 0; s >>= 1) {
        if (threadIdx.x < s) red[threadIdx.x] = fmaxf(red[threadIdx.x], red[threadIdx.x + s]);
        __syncthreads();
    }
    if (threadIdx.x == 0) magmax[blockIdx.x] = red[0];
}

// =====================================================================
// NMS: division-free compares on RAW mag in LDS; 4 px/lane, uchar4
// bucket loads, nibble-LDS word assembly -> Mb (tile-major bitmask).
// Exactness: monotone RN(.)/M + 1.0000005f gap + rare exact divide
// fallback under wave-uniform __any.
// =====================================================================
__global__ __launch_bounds__(256, 6) void k_nms_b(const float* __restrict__ mag,
                                                  const unsigned char* __restrict__ bucket,
                                                  const float* __restrict__ magmax,
                                                  u64* __restrict__ Mb,
                                                  float* __restrict__ partial) {
#pragma clang fp contract(off)
    __shared__ float sN[34 * 136];
    __shared__ unsigned int nib32[256];
    __shared__ float red[256];

    const int tid = threadIdx.x;
    const int x0 = blockIdx.x * 128;
    const int y0 = blockIdx.y * 32;
    const int b = blockIdx.z;
    const size_t base = (size_t)b * HW;
    const float M = magmax[b];

    for (int idx = tid; idx < 34 * 34; idx += 256) {
        int r = idx / 34, v = idx - r * 34;
        int gy = y0 - 1 + r;
        int gxv = x0 - 4 + v * 4;
        float4 val = make_float4(0.f, 0.f, 0.f, 0.f);
        if (gy >= 0 && gy < H && gxv >= 0 && gxv <= W - 4)
            val = *(const float4*)&mag[base + (size_t)gy * W + gxv];
        *(float4*)&sN[r * 136 + v * 4] = val;
    }
    __syncthreads();

    const int r = tid >> 5;             // row within 8-row slab
    const int cg = (tid & 31) * 4;
    float amax = 0.0f;

    for (int k4 = 0; k4 < 4; ++k4) {
        const int rr = k4 * 8 + r;      // 0..31
        const int y = y0 + rr;
        unsigned int bk4 = *(const unsigned int*)&bucket[base + (size_t)y * W + x0 + cg];
        float4 a4 = *(const float4*)&sN[(rr + 1) * 136 + cg + 4];
        float av[4] = {a4.x, a4.y, a4.z, a4.w};
        bool im[4];
        bool bad = false;
        float bpv[4], bnv[4];
        bool g1v[4], g2v[4], f1v[4], f2v[4];
#pragma unroll
        for (int j = 0; j < 4; ++j) {
            int c = cg + j;
            int bkt = (bk4 >> (8 * j)) & 0xff;
            int dy = NBDY[bkt], dx = NBDX[bkt];
            float a = av[j];
            float bp = sN[(rr + 1 + dy) * 136 + c + 4 + dx];
            float bn = sN[(rr + 1 - dy) * 136 + c + 4 - dx];
            bpv[j] = bp; bnv[j] = bn;
            bool g1 = a > bp, g2 = a > bn;
            bool f1 = a >= bp * 1.0000005f;
            bool f2 = a >= bn * 1.0000005f;
            g1v[j] = g1; g2v[j] = g2; f1v[j] = f1; f2v[j] = f2;
            im[j] = g1 && g2;
            bad = bad || (g1 && !f1) || (g2 && !f2);
        }
        if (__any(bad)) {
#pragma unroll
            for (int j = 0; j < 4; ++j) {
                bool b1 = g1v[j] && !f1v[j];
                bool b2 = g2v[j] && !f2v[j];
                if (b1 || b2) {
                    float qa = av[j] / M;
                    bool r1 = g1v[j], r2 = g2v[j];
                    if (b1) r1 = qa > (bpv[j] / M);
                    if (b2) r2 = qa > (bnv[j] / M);
                    im[j] = r1 && r2;
                }
            }
        }
        unsigned int nib = 0;
#pragma unroll
        for (int j = 0; j < 4; ++j) {
            if (im[j]) { nib |= 1u << j; amax = fmaxf(amax, av[j]); }
        }
        nib32[tid] = nib;
        __syncthreads();
        if (tid < 16) {
            int rw = tid >> 1, h = tid & 1;
            u64 w = 0;
#pragma unroll
            for (int j = 0; j < 16; ++j)
                w |= (u64)nib32[rw * 32 + h * 16 + j] << (4 * j);
            int yy = y0 + k4 * 8 + rw;
            int widx = ((b << 8) | ((yy >> 6) << 4) | ((x0 >> 6) + h)) * 64 + (yy & 63);
            Mb[widx] = w;
        }
        __syncthreads();
    }

    red[tid] = amax;
    __syncthreads();
    for (int s = 128; s > 0; s >>= 1) {
        if (tid < s) red[tid] = fmaxf(red[tid], red[tid + s]);
        __syncthreads();
    }
    // max(thin) over block = RN(max_surviving_a / M): RN monotone => exact
    if (tid == 0)
        partial[(blockIdx.z * 32 + blockIdx.y) * 8 + blockIdx.x] = red[0] / M;
}

// ---------------- global thin-max + per-image threshold bisection ----------------
__global__ __launch_bounds__(1024) void k_finalize_thr(const float* __restrict__ partial,
                                                       float* __restrict__ hdr,
                                                       float* __restrict__ thr) {
    __shared__ float red[1024];
    float m = 0.0f;
    for (int k = threadIdx.x; k < 4096; k += 1024) m = fmaxf(m, partial[k]);
    red[threadIdx.x] = m;
    __syncthreads();
    for (int s = 512; s > 0; s >>= 1) {
        if (threadIdx.x < s) red[threadIdx.x] = fmaxf(red[threadIdx.x], red[threadIdx.x + s]);
        __syncthreads();
    }
    if (threadIdx.x == 0) hdr[16] = red[0];
    if (threadIdx.x < 32) {
        float tm = red[0];
        int t = threadIdx.x;
        float M = hdr[t >> 1];
        float T = (t & 1) ? (tm * 0.15f) : 0.00392f;
        if (0.0f / M >= T) { thr[t] = 0.0f; return; }
        unsigned int lo = 0u, hi = 0x7f800000u;
        while (hi - lo > 1u) {
            unsigned int mid = lo + ((hi - lo) >> 1);
            if (__uint_as_float(mid) / M >= T) hi = mid; else lo = mid;
        }
        thr[t] = __uint_as_float(hi);
    }
}

// ---------------- threshold: mag + is_max bits -> Sb/Wb (no division) ----------------
__global__ __launch_bounds__(256, 8) void k_thresh_b(const float* __restrict__ mag,
                                                     const u64* __restrict__ Mb,
                                                     const float* __restrict__ hdr,
                                                     const float* __restrict__ thr,
                                                     u64* __restrict__ Sb,
                                                     u64* __restrict__ Wb) {
    __shared__ unsigned int nibS[256], nibW[256];
    const int tid = threadIdx.x;
    const int x0 = blockIdx.x * 128;
    const int y0 = blockIdx.y * 32;
    const int b = blockIdx.z;
    const size_t base = (size_t)b * HW;
    const float Alo = thr[b * 2], Ahi = thr[b * 2 + 1];
    const bool snm = (hdr[16] * 0.15f <= 0.0f);
    const int r = tid >> 5;
    const int cg = (tid & 31) * 4;
    const int hl = cg >> 6;

    for (int k4 = 0; k4 < 4; ++k4) {
        const int rr = k4 * 8 + r;
        const int y = y0 + rr;
        float4 a4 = *(const float4*)&mag[base + (size_t)y * W + x0 + cg];
        float av[4] = {a4.x, a4.y, a4.z, a4.w};
        const int widx = ((b << 8) | ((y >> 6) << 4) | ((x0 >> 6) + hl)) * 64 + (y & 63);
        u64 mw = Mb[widx];
        unsigned int ns = 0, nw = 0;
#pragma unroll
        for (int j = 0; j < 4; ++j) {
            bool im = (mw >> ((cg & 63) + j)) & 1ull;
            bool strong = snm || (im && (av[j] >= Ahi));
            bool weak = (!strong) && im && (av[j] >= Alo);
            ns |= (strong ? 1u : 0u) << j;
            nw |= (weak ? 1u : 0u) << j;
        }
        nibS[tid] = ns;
        nibW[tid] = nw;
        __syncthreads();
        if (tid < 32) {
            bool isW = (tid >= 16);
            int t = tid & 15;
            int rw = t >> 1, h = t & 1;
            const unsigned int* nb = isW ? nibW : nibS;
            u64 w = 0;
#pragma unroll
            for (int j = 0; j < 16; ++j)
                w |= (u64)nb[rw * 32 + h * 16 + j] << (4 * j);
            int yy = y0 + k4 * 8 + rw;
            int widx2 = ((b << 8) | ((yy >> 6) << 4) | ((x0 >> 6) + h)) * 64 + (yy & 63);
            if (isW) Wb[widx2] = w; else Sb[widx2] = w;
        }
        __syncthreads();
    }
}

// ---------------- hysteresis: bit-parallel 64x64 tile per wave, tile-major ----------------
// H-KS variant (verified exact in r8: passed, absmax=0; remainder 140 vs 144
// plain). Per iteration: horizontal Kogge-Stone flood through weak runs +
// one vertical step. Each accel iteration SUPERSET of one plain iteration,
// SUBSET of true closure => per-pass result sandwiched between plain-160 and
// global closure (both = reference) => bit-identical. Constant cross-tile
// terms (hstat/halo) injected once before the loop (fixpoint-equivalent).
// [r9: adding V-KS regressed +27 us (24 serially-dependent shfls/iter,
//  staircase depth doesn't collapse) -- do not re-add.]
template <bool LAST>
__global__ __launch_bounds__(256) void k_hyster_bits(const u64* __restrict__ Wb,
                                                     u64* __restrict__ Sb,
                                                     float* __restrict__ out) {
    const int lane = threadIdx.x & 63;
    const int t = blockIdx.x * 4 + (threadIdx.x >> 6);  // tile id = b*256+ty*16+tx
    const int ty = (t >> 4) & 15;
    const int tx = t & 15;
    const int idx = t * 64 + lane;

    u64 S = Sb[idx];
    const u64 Wk = Wb[idx];

    u64 hstat = 0;
    if (tx > 0)  hstat |= (Sb[(t - 1) * 64 + lane] >> 63) & 1ull;
    if (tx < 15) hstat |= (Sb[(t + 1) * 64 + lane] & 1ull) << 63;

    u64 halo = 0;
    if (lane == 0 && ty > 0) {
        const int ta = t - 16;
        u64 tc = Sb[ta * 64 + 63];
        u64 hh = (tc << 1) | tc | (tc >> 1);
        if (tx > 0)  hh |= (Sb[(ta - 1) * 64 + 63] >> 63) & 1ull;
        if (tx < 15) hh |= (Sb[(ta + 1) * 64 + 63] & 1ull) << 63;
        halo = hh;
    }
    if (lane == 63 && ty < 15) {
        const int tb = t + 16;
        u64 tc = Sb[tb * 64 + 0];
        u64 hh = (tc << 1) | tc | (tc >> 1);
        if (tx > 0)  hh |= (Sb[(tb - 1) * 64 + 0] >> 63) & 1ull;
        if (tx < 15) hh |= (Sb[(tb + 1) * 64 + 0] & 1ull) << 63;
        halo = hh;
    }

    // one-time injection of constant external sources (hstat own/up/dn + halo)
    {
        u64 eu = __shfl_up(hstat, 1, 64);
        u64 ed = __shfl_down(hstat, 1, 64);
        if (lane == 0)  eu = halo;
        if (lane == 63) ed = halo;
        S |= Wk & (hstat | eu | ed);
    }

    for (int it = 0; it < 160; ++it) {
        // horizontal flood of S through weak runs (Kogge-Stone, both dirs)
        u64 x = S;
        x |= (x << 1) & Wk;
        x |= (x >> 1) & Wk;
        u64 pL = Wk & (Wk << 1);
        u64 pR = Wk & (Wk >> 1);
        x |= (x << 2) & pL;   x |= (x >> 2) & pR;
        pL &= pL << 2;        pR &= pR >> 2;
        x |= (x << 4) & pL;   x |= (x >> 4) & pR;
        pL &= pL << 4;        pR &= pR >> 4;
        x |= (x << 8) & pL;   x |= (x >> 8) & pR;
        pL &= pL << 8;        pR &= pR >> 8;
        x |= (x << 16) & pL;  x |= (x >> 16) & pR;
        pL &= pL << 16;       pR &= pR >> 16;
        x |= (x << 32) & pL;  x |= (x >> 32) & pR;
        // vertical single step (hh includes +-1 spill for diagonal adjacency)
        u64 hh = x | (x << 1) | (x >> 1);
        u64 up = __shfl_up(hh, 1, 64);
        if (lane == 0) up = 0;
        u64 dn = __shfl_down(hh, 1, 64);
        if (lane == 63) dn = 0;
        u64 nS = x | (Wk & (up | dn));
        bool ch = (nS != S);
        S = nS;
        if (!__any(ch)) break;
    }

    if (!LAST) {
        Sb[idx] = S;
    } else {
        const int bimg = t >> 8;
        float* op = out + (size_t)bimg * HW + (size_t)(ty * 64) * W + tx * 64 + lane;
#pragma unroll 4
        for (int rr = 0; rr < 64; ++rr) {
            u64 wrow = __shfl(S, rr, 64);
            op[(size_t)rr * W] = ((wrow >> lane) & 1ull) ? 255.0f : 0.0f;
        }
    }
}

extern "C" void kernel_launch(void* const* d_in, const int* in_sizes, int n_in,
                              void* d_out, int out_size, void* d_ws, size_t ws_size,
                              hipStream_t stream) {
    (void)in_sizes; (void)n_in; (void)out_size; (void)ws_size;
    const float* img = (const float*)d_in[0];
    float* out = (float*)d_out;

    // workspace layout
    float* hdr = (float*)d_ws;                 // [0..15]=magmax, [16]=thinmax
    float* thr = hdr + 64;                     // 32 floats: per-image Alo/Ahi
    float* partialA = hdr + 128;               // 16384 floats (K1 blocks)
    float* partialB = partialA + 16384;        // 4096 floats (nms blocks)
    float* A = partialB + 4096;                // mag, 64 MB (16B-aligned)
    unsigned char* C = (unsigned char*)(A + (size_t)NTOT);  // bucket, 16 MB
    u64* Sb = (u64*)(C + (size_t)NTOT);        // strong bits, 2 MB
    u64* Wb = Sb + NTOT / 64;                  // weak bits, 2 MB
    u64* Mb = Wb + NTOT / 64;                  // is_max bits, 2 MB

    dim3 blk(256);
    k_smooth_sobel<<<dim3(8, 128, BB), blk, 0, stream>>>(img, A, C, partialA);
    k_redmax_img<<<dim3(BB), blk, 0, stream>>>(partialA, hdr);
    k_nms_b<<<dim3(8, 32, BB), blk, 0, stream>>>(A, C, hdr, Mb, partialB);
    k_finalize_thr<<<dim3(1), dim3(1024), 0, stream>>>(partialB, hdr, thr);
    k_thresh_b<<<dim3(8, 32, BB), blk, 0, stream>>>(A, Mb, hdr, thr, Sb, Wb);
    for (int p = 0; p < 5; ++p)
        k_hyster_bits<false><<<dim3(NTOT / (64 * 64) / 4), blk, 0, stream>>>(Wb, Sb, out);
    k_hyster_bits<true><<<dim3(NTOT / (64 * 64) / 4), blk, 0, stream>>>(Wb, Sb, out);
}